// Round 1
// baseline (830.009 us; speedup 1.0000x reference)
//
#include <hip/hip_runtime.h>
#include <hip/hip_bf16.h>

#define NN 50000
#define EE 800000
#define NTILES 782   // ceil(50000/64)

typedef __bf16 bf16x8 __attribute__((ext_vector_type(8)));
typedef unsigned short us8 __attribute__((ext_vector_type(8)));
typedef float f32x4 __attribute__((ext_vector_type(4)));

__device__ __forceinline__ unsigned short f2bf(float f) {
  unsigned u = __float_as_uint(f);
  u += 0x7FFFu + ((u >> 16) & 1u);           // round-to-nearest-even
  return (unsigned short)(u >> 16);
}
__device__ __forceinline__ float bflo(unsigned u) { return __uint_as_float(u << 16); }
__device__ __forceinline__ float bfhi(unsigned u) { return __uint_as_float(u & 0xFFFF0000u); }
__device__ __forceinline__ float bf2f(unsigned short h) { return __uint_as_float(((unsigned)h) << 16); }
__device__ __forceinline__ float fast_tanh(float x) {
  float e = __expf(2.0f * x);
  return 1.0f - 2.0f / (e + 1.0f);
}

// ---------------- graph setup ----------------

__global__ __launch_bounds__(256) void k_count(const int* __restrict__ ei,
                                               int* __restrict__ cntA, int* __restrict__ cntB) {
  int i = blockIdx.x * 256 + threadIdx.x;       // EE = 3125*256 exactly
  int s = ei[i];
  int d = ei[EE + i];
  atomicAdd(&cntA[d], 1);
  atomicAdd(&cntB[s], 1);
}

__global__ __launch_bounds__(256) void k_scan1(const int* __restrict__ cntA,
                                               const int* __restrict__ cntB,
                                               int* __restrict__ part) {
  const int CH = 196;
  int z = blockIdx.y;
  const int* c = z ? cntB : cntA;
  __shared__ int sd[256];
  int t = threadIdx.x;
  int idx = blockIdx.x * CH + t;
  int v = (t < CH && idx < NN) ? c[idx] : 0;
  sd[t] = v; __syncthreads();
  for (int s = 128; s > 0; s >>= 1) { if (t < s) sd[t] += sd[t + s]; __syncthreads(); }
  if (t == 0) part[z * 256 + blockIdx.x] = sd[0];
}

__global__ __launch_bounds__(256) void k_scan2(int* __restrict__ part) {
  int z = blockIdx.x;
  __shared__ int sd[256];
  int t = threadIdx.x;
  sd[t] = part[z * 256 + t]; __syncthreads();
  for (int o = 1; o < 256; o <<= 1) {
    int x = (t >= o) ? sd[t - o] : 0;
    __syncthreads();
    sd[t] += x;
    __syncthreads();
  }
  int ex = (t > 0) ? sd[t - 1] : 0;
  part[z * 256 + t] = ex;
}

__global__ __launch_bounds__(256) void k_scan3(const int* __restrict__ cntA,
                                               const int* __restrict__ cntB,
                                               const int* __restrict__ part,
                                               int* __restrict__ rpA, int* __restrict__ rpB,
                                               int* __restrict__ curA, int* __restrict__ curB,
                                               float* __restrict__ dinvA, float* __restrict__ dinvB) {
  const int CH = 196;
  int z = blockIdx.y;
  const int* c = z ? cntB : cntA;
  int* rp  = z ? rpB  : rpA;
  int* cur = z ? curB : curA;
  float* dinv = z ? dinvB : dinvA;
  __shared__ int sd[256];
  int t = threadIdx.x;
  int idx = blockIdx.x * CH + t;
  bool act = (t < CH && idx < NN);
  int v = act ? c[idx] : 0;
  sd[t] = v; __syncthreads();
  for (int o = 1; o < 256; o <<= 1) {
    int x = (t >= o) ? sd[t - o] : 0;
    __syncthreads();
    sd[t] += x;
    __syncthreads();
  }
  int ex = (t > 0 ? sd[t - 1] : 0) + part[z * 256 + blockIdx.x];
  if (act) {
    rp[idx] = ex;
    cur[idx] = ex;
    dinv[idx] = rsqrtf((float)(v + 1));   // +1 self loop; always > 0
  }
  if (blockIdx.x == 255 && t == 0) rp[NN] = EE;
}

__global__ __launch_bounds__(256) void k_fill(const int* __restrict__ ei,
                                              int* __restrict__ curA, int* __restrict__ curB,
                                              int* __restrict__ colA, int* __restrict__ colB) {
  int i = blockIdx.x * 256 + threadIdx.x;
  int s = ei[i];
  int d = ei[EE + i];
  int pa = atomicAdd(&curA[d], 1); colA[pa] = s;  // CSR keyed by dst, stores src
  int pb = atomicAdd(&curB[s], 1); colB[pb] = d;  // CSR keyed by src, stores dst
}

// ---------------- fused 3-power GEMM:  Z = Hin @ [w0|w1|w2]  (M=50000,K,N=192) ----------------
// b-fragments (whole K) kept in registers; A tile staged in LDS; persistent blocks.

template<int K, bool F32IN>
__global__ __launch_bounds__(256) void k_gemm(const void* __restrict__ in0, const void* __restrict__ in1,
                                              const float* __restrict__ W0, const float* __restrict__ W1,
                                              unsigned short* __restrict__ Z0, unsigned short* __restrict__ Z1) {
  constexpr int KS = K / 32;
  constexpr int KP = K + 8;
  __shared__ unsigned short A_lds[64 * KP];

  int z = blockIdx.y;
  const void* Ain = z ? in1 : in0;
  const float* W = z ? W1 : W0;
  unsigned short* Zo = z ? Z1 : Z0;

  int t = threadIdx.x;
  int lane = t & 63, wv = t >> 6;
  int nloc = lane & 15, quad = lane >> 4;

  // preload all B fragments for this wave's 48 columns (3 n-tiles x KS k-steps)
  bf16x8 b[3][KS];
#pragma unroll
  for (int nt = 0; nt < 3; ++nt) {
    int ncol = wv * 48 + nt * 16 + nloc;                 // 0..191
    const float* wp = W + (ncol >> 6) * (K * 64) + (ncol & 63);
#pragma unroll
    for (int ks = 0; ks < KS; ++ks) {
      int kb = ks * 32 + quad * 8;
      us8 u;
#pragma unroll
      for (int i = 0; i < 8; ++i) u[i] = f2bf(wp[(kb + i) * 64]);
      b[nt][ks] = __builtin_bit_cast(bf16x8, u);
    }
  }

  for (int bm = blockIdx.x; bm < NTILES; bm += gridDim.x) {
    int m0 = bm * 64;
    __syncthreads();
    // stage A tile (64 x K) into LDS as bf16, padded rows
#pragma unroll
    for (int it = 0; it < KS; ++it) {                    // KS*256 = 64*(K/8) chunks of 8
      int c = it * 256 + t;
      int row = c / (K / 8);
      int kc  = c % (K / 8);
      int gr = m0 + row;
      us8 val;
      if (F32IN) {
        float4 v0 = make_float4(0, 0, 0, 0), v1 = make_float4(0, 0, 0, 0);
        if (gr < NN) {
          const float* Af = (const float*)Ain + (size_t)gr * K + kc * 8;
          v0 = *(const float4*)(Af);
          v1 = *(const float4*)(Af + 4);
        }
        val[0] = f2bf(v0.x); val[1] = f2bf(v0.y); val[2] = f2bf(v0.z); val[3] = f2bf(v0.w);
        val[4] = f2bf(v1.x); val[5] = f2bf(v1.y); val[6] = f2bf(v1.z); val[7] = f2bf(v1.w);
      } else {
        if (gr < NN) val = *(const us8*)((const unsigned short*)Ain + (size_t)gr * K + kc * 8);
        else         val = (us8)0;
      }
      *(us8*)(&A_lds[row * KP + kc * 8]) = val;
    }
    __syncthreads();

    f32x4 acc[4][3];
#pragma unroll
    for (int mt = 0; mt < 4; ++mt)
#pragma unroll
      for (int nt = 0; nt < 3; ++nt) acc[mt][nt] = (f32x4){0.f, 0.f, 0.f, 0.f};

#pragma unroll
    for (int ks = 0; ks < KS; ++ks) {
      bf16x8 a[4];
#pragma unroll
      for (int mt = 0; mt < 4; ++mt)
        a[mt] = *(const bf16x8*)(&A_lds[(mt * 16 + nloc) * KP + ks * 32 + quad * 8]);
#pragma unroll
      for (int mt = 0; mt < 4; ++mt)
#pragma unroll
        for (int nt = 0; nt < 3; ++nt)
          acc[mt][nt] = __builtin_amdgcn_mfma_f32_16x16x32_bf16(a[mt], b[nt][ks], acc[mt][nt], 0, 0, 0);
    }

    // epilogue: D row = quad*4 + r, col = nloc (within n-tile)
#pragma unroll
    for (int mt = 0; mt < 4; ++mt) {
      int rowb = m0 + mt * 16 + quad * 4;
#pragma unroll
      for (int nt = 0; nt < 3; ++nt) {
        int colg = wv * 48 + nt * 16 + nloc;
#pragma unroll
        for (int r = 0; r < 4; ++r) {
          int rr = rowb + r;
          if (rr < NN) Zo[(size_t)rr * 192 + colg] = f2bf(acc[mt][nt][r]);
        }
      }
    }
  }
}

// ---------------- prop1: T = Ahat * Z[:,64:192]  (128 cols, bf16) ----------------
// one wave per destination node; lane handles 2 columns (uint = 2 bf16)

__global__ __launch_bounds__(256) void k_prop1(const unsigned short* __restrict__ Z0,
                                               const unsigned short* __restrict__ Z1,
                                               unsigned short* __restrict__ T0,
                                               unsigned short* __restrict__ T1,
                                               const int* __restrict__ rpA, const int* __restrict__ rpB,
                                               const int* __restrict__ colA, const int* __restrict__ colB,
                                               const float* __restrict__ dinvA, const float* __restrict__ dinvB) {
  int z = blockIdx.y;
  const unsigned short* Z = z ? Z1 : Z0;
  unsigned short* T = z ? T1 : T0;
  const int* rp = z ? rpB : rpA;
  const int* col = z ? colB : colA;
  const float* dinv = z ? dinvB : dinvA;

  int wv = threadIdx.x >> 6, lane = threadIdx.x & 63;
  int v = blockIdx.x * 4 + wv;
  if (v >= NN) return;
  v = __builtin_amdgcn_readfirstlane(v);

  int e0 = rp[v], e1 = rp[v + 1];
  float dv = dinv[v];

  unsigned selfv = ((const unsigned*)(Z + (size_t)v * 192 + 64))[lane];
  float ax = bflo(selfv) * dv, ay = bfhi(selfv) * dv;

  int e = e0;
  for (; e + 2 <= e1; e += 2) {
    int s0 = col[e], s1 = col[e + 1];
    float d0 = dinv[s0], d1 = dinv[s1];
    unsigned p0 = ((const unsigned*)(Z + (size_t)s0 * 192 + 64))[lane];
    unsigned p1 = ((const unsigned*)(Z + (size_t)s1 * 192 + 64))[lane];
    ax += d0 * bflo(p0) + d1 * bflo(p1);
    ay += d0 * bfhi(p0) + d1 * bfhi(p1);
  }
  if (e < e1) {
    int s0 = col[e];
    float d0 = dinv[s0];
    unsigned p0 = ((const unsigned*)(Z + (size_t)s0 * 192 + 64))[lane];
    ax += d0 * bflo(p0);
    ay += d0 * bfhi(p0);
  }
  ax *= dv; ay *= dv;
  unsigned o = (unsigned)f2bf(ax) | ((unsigned)f2bf(ay) << 16);
  ((unsigned*)(T + (size_t)v * 128))[lane] = o;
}

// ---------------- combine: U = Ahat * T[:,64:128]; out = tanh([Z0+b0 | T0+b1 | U+b2]) ----------------

template<bool FINAL>
__global__ __launch_bounds__(256) void k_combine(const unsigned short* __restrict__ Z0,
                                                 const unsigned short* __restrict__ Z1,
                                                 const unsigned short* __restrict__ T0,
                                                 const unsigned short* __restrict__ T1,
                                                 unsigned short* __restrict__ H0,
                                                 unsigned short* __restrict__ H1,
                                                 float* __restrict__ out,
                                                 const float* __restrict__ bia0, const float* __restrict__ bia1,
                                                 const int* __restrict__ rpA, const int* __restrict__ rpB,
                                                 const int* __restrict__ colA, const int* __restrict__ colB,
                                                 const float* __restrict__ dinvA, const float* __restrict__ dinvB) {
  int z = blockIdx.y;
  const unsigned short* Z = z ? Z1 : Z0;
  const unsigned short* T = z ? T1 : T0;
  unsigned short* H = z ? H1 : H0;
  const float* bias = z ? bia1 : bia0;
  const int* rp = z ? rpB : rpA;
  const int* col = z ? colB : colA;
  const float* dinv = z ? dinvB : dinvA;

  int wv = threadIdx.x >> 6, lane = threadIdx.x & 63;
  int v = blockIdx.x * 4 + wv;
  if (v >= NN) return;
  v = __builtin_amdgcn_readfirstlane(v);

  int e0 = rp[v], e1 = rp[v + 1];
  float dv = dinv[v];

  const unsigned short* Trow = T + (size_t)v * 128;
  float u = dv * bf2f(Trow[64 + lane]);   // self loop

  int e = e0;
  for (; e + 2 <= e1; e += 2) {
    int s0 = col[e], s1 = col[e + 1];
    float d0 = dinv[s0], d1 = dinv[s1];
    float t0 = bf2f(T[(size_t)s0 * 128 + 64 + lane]);
    float t1 = bf2f(T[(size_t)s1 * 128 + 64 + lane]);
    u += d0 * t0 + d1 * t1;
  }
  if (e < e1) {
    int s0 = col[e];
    u += dinv[s0] * bf2f(T[(size_t)s0 * 128 + 64 + lane]);
  }
  u *= dv;

  float p0 = fast_tanh(bf2f(Z[(size_t)v * 192 + lane]) + bias[lane]);
  float p1 = fast_tanh(bf2f(Trow[lane]) + bias[64 + lane]);
  float p2 = fast_tanh(u + bias[128 + lane]);

  if (FINAL) {
    float* o = out + (size_t)z * NN * 192 + (size_t)v * 192;
    o[lane] = p0; o[lane + 64] = p1; o[lane + 128] = p2;
  } else {
    unsigned short* h = H + (size_t)v * 192;
    h[lane] = f2bf(p0); h[lane + 64] = f2bf(p1); h[lane + 128] = f2bf(p2);
  }
}

// ---------------- host ----------------

extern "C" void kernel_launch(void* const* d_in, const int* in_sizes, int n_in,
                              void* d_out, int out_size, void* d_ws, size_t ws_size,
                              hipStream_t stream) {
  const float* x  = (const float*)d_in[0];
  const int* ei   = (const int*)d_in[1];
  const float* wout1 = (const float*)d_in[2];
  const float* bout1 = (const float*)d_in[3];
  const float* wout2 = (const float*)d_in[4];
  const float* bout2 = (const float*)d_in[5];
  const float* wout3 = (const float*)d_in[6];
  const float* bout3 = (const float*)d_in[7];
  const float* win1  = (const float*)d_in[8];
  const float* bin1  = (const float*)d_in[9];
  const float* win2  = (const float*)d_in[10];
  const float* bin2  = (const float*)d_in[11];
  const float* win3  = (const float*)d_in[12];
  const float* bin3  = (const float*)d_in[13];
  float* out = (float*)d_out;

  char* p = (char*)d_ws;
  auto alloc = [&](size_t bytes) { char* r = p; p += (bytes + 255) & ~(size_t)255; return r; };
  int* cnt   = (int*)alloc((size_t)2 * NN * 4);       // cntA | cntB contiguous (one memset)
  int* cntA  = cnt;
  int* cntB  = cnt + NN;
  int* rpA   = (int*)alloc((size_t)(NN + 1) * 4);
  int* rpB   = (int*)alloc((size_t)(NN + 1) * 4);
  int* curA  = (int*)alloc((size_t)NN * 4);
  int* curB  = (int*)alloc((size_t)NN * 4);
  int* colA  = (int*)alloc((size_t)EE * 4);
  int* colB  = (int*)alloc((size_t)EE * 4);
  float* dinvA = (float*)alloc((size_t)NN * 4);
  float* dinvB = (float*)alloc((size_t)NN * 4);
  int* part  = (int*)alloc(512 * 4);
  unsigned short* Z0 = (unsigned short*)alloc((size_t)NN * 192 * 2);
  unsigned short* Z1 = (unsigned short*)alloc((size_t)NN * 192 * 2);
  unsigned short* T0 = (unsigned short*)alloc((size_t)NN * 128 * 2);
  unsigned short* T1 = (unsigned short*)alloc((size_t)NN * 128 * 2);
  unsigned short* H0 = (unsigned short*)alloc((size_t)NN * 192 * 2);
  unsigned short* H1 = (unsigned short*)alloc((size_t)NN * 192 * 2);

  // ---- graph build ----
  hipMemsetAsync(cnt, 0, (size_t)2 * NN * 4, stream);
  k_count<<<EE / 256, 256, 0, stream>>>(ei, cntA, cntB);
  k_scan1<<<dim3(256, 2), 256, 0, stream>>>(cntA, cntB, part);
  k_scan2<<<2, 256, 0, stream>>>(part);
  k_scan3<<<dim3(256, 2), 256, 0, stream>>>(cntA, cntB, part, rpA, rpB, curA, curB, dinvA, dinvB);
  k_fill<<<EE / 256, 256, 0, stream>>>(ei, curA, curB, colA, colB);

  dim3 gGemm(196, 2);     // persistent: ~4 M-tiles per block, amortizes W preload
  dim3 gProp(12500, 2);   // 4 nodes (waves) per block

  // ---- layer 1 (K=256, fp32 input x shared by both encoders) ----
  k_gemm<256, true><<<gGemm, 256, 0, stream>>>(x, x, wout1, win1, Z0, Z1);
  k_prop1<<<gProp, 256, 0, stream>>>(Z0, Z1, T0, T1, rpA, rpB, colA, colB, dinvA, dinvB);
  k_combine<false><<<gProp, 256, 0, stream>>>(Z0, Z1, T0, T1, H0, H1, nullptr, bout1, bin1,
                                              rpA, rpB, colA, colB, dinvA, dinvB);
  // ---- layer 2 (K=192) ----
  k_gemm<192, false><<<gGemm, 256, 0, stream>>>(H0, H1, wout2, win2, Z0, Z1);
  k_prop1<<<gProp, 256, 0, stream>>>(Z0, Z1, T0, T1, rpA, rpB, colA, colB, dinvA, dinvB);
  k_combine<false><<<gProp, 256, 0, stream>>>(Z0, Z1, T0, T1, H0, H1, nullptr, bout2, bin2,
                                              rpA, rpB, colA, colB, dinvA, dinvB);
  // ---- layer 3 (K=192, writes fp32 d_out) ----
  k_gemm<192, false><<<gGemm, 256, 0, stream>>>(H0, H1, wout3, win3, Z0, Z1);
  k_prop1<<<gProp, 256, 0, stream>>>(Z0, Z1, T0, T1, rpA, rpB, colA, colB, dinvA, dinvB);
  k_combine<true><<<gProp, 256, 0, stream>>>(Z0, Z1, T0, T1, H0, H1, out, bout3, bin3,
                                             rpA, rpB, colA, colB, dinvA, dinvB);
}

// Round 2
// 688.239 us; speedup vs baseline: 1.2060x; 1.2060x over previous
//
#include <hip/hip_runtime.h>
#include <hip/hip_bf16.h>

#define NN 50000
#define EE 800000
#define NTILES 782   // ceil(50000/64)
#define NB 391       // ceil(50000/128) buckets of 128 nodes

typedef __bf16 bf16x8 __attribute__((ext_vector_type(8)));
typedef unsigned short us8 __attribute__((ext_vector_type(8)));
typedef float f32x4 __attribute__((ext_vector_type(4)));

__device__ __forceinline__ unsigned short f2bf(float f) {
  unsigned u = __float_as_uint(f);
  u += 0x7FFFu + ((u >> 16) & 1u);           // round-to-nearest-even
  return (unsigned short)(u >> 16);
}
__device__ __forceinline__ float bflo(unsigned u) { return __uint_as_float(u << 16); }
__device__ __forceinline__ float bfhi(unsigned u) { return __uint_as_float(u & 0xFFFF0000u); }
__device__ __forceinline__ float bf2f(unsigned short h) { return __uint_as_float(((unsigned)h) << 16); }
__device__ __forceinline__ float fast_tanh(float x) {
  float e = __expf(2.0f * x);
  return 1.0f - 2.0f / (e + 1.0f);
}

// ---------------- bucketed CSR build ----------------
// bucket = node >> 7 (128 nodes/bucket). Direction A keyed by dst (payload src),
// direction B keyed by src (payload dst). bCnt/bCur layout: [z*NB + b].

__global__ __launch_bounds__(256) void k_hist(const int* __restrict__ ei, int* __restrict__ bCnt) {
  __shared__ int h[2 * NB];
  for (int i = threadIdx.x; i < 2 * NB; i += 256) h[i] = 0;
  __syncthreads();
  int base = blockIdx.x * 2048;
#pragma unroll
  for (int j = 0; j < 8; ++j) {
    int e = base + j * 256 + threadIdx.x;
    if (e < EE) {
      int s = ei[e], d = ei[EE + e];
      atomicAdd(&h[d >> 7], 1);
      atomicAdd(&h[NB + (s >> 7)], 1);
    }
  }
  __syncthreads();
  for (int i = threadIdx.x; i < 2 * NB; i += 256) {
    int c = h[i];
    if (c) atomicAdd(&bCnt[i], c);
  }
}

__global__ __launch_bounds__(512) void k_bscan(const int* __restrict__ bCnt,
                                               int* __restrict__ bOff, int* __restrict__ bCur) {
  __shared__ int sd[512];
  int z = blockIdx.x, t = threadIdx.x;
  sd[t] = (t < NB) ? bCnt[z * NB + t] : 0;
  __syncthreads();
  for (int o = 1; o < 512; o <<= 1) {
    int v = (t >= o) ? sd[t - o] : 0;
    __syncthreads();
    sd[t] += v;
    __syncthreads();
  }
  int ex = (t > 0) ? sd[t - 1] : 0;
  if (t < NB) { bOff[z * (NB + 1) + t] = ex; bCur[z * NB + t] = ex; }
  if (t == NB) bOff[z * (NB + 1) + NB] = ex;   // = total = EE
}

__global__ __launch_bounds__(256) void k_scatter(const int* __restrict__ ei,
                                                 int* __restrict__ bCur,
                                                 unsigned* __restrict__ binA,
                                                 unsigned* __restrict__ binB) {
  __shared__ int h[2 * NB];
  for (int i = threadIdx.x; i < 2 * NB; i += 256) h[i] = 0;
  __syncthreads();
  int base = blockIdx.x * 2048;
  int s[8], d[8], la[8], lb[8];
#pragma unroll
  for (int j = 0; j < 8; ++j) {
    int e = base + j * 256 + threadIdx.x;
    d[j] = -1;
    if (e < EE) {
      s[j] = ei[e]; d[j] = ei[EE + e];
      la[j] = atomicAdd(&h[d[j] >> 7], 1);
      lb[j] = atomicAdd(&h[NB + (s[j] >> 7)], 1);
    }
  }
  __syncthreads();
  // reserve global ranges, store base back into h
  for (int i = threadIdx.x; i < 2 * NB; i += 256) {
    int c = h[i];
    if (c) h[i] = atomicAdd(&bCur[i], c);
  }
  __syncthreads();
#pragma unroll
  for (int j = 0; j < 8; ++j) {
    if (d[j] >= 0) {
      int pa = h[d[j] >> 7] + la[j];
      binA[pa] = ((unsigned)s[j] << 7) | (unsigned)(d[j] & 127);
      int pb = h[NB + (s[j] >> 7)] + lb[j];
      binB[pb] = ((unsigned)d[j] << 7) | (unsigned)(s[j] & 127);
    }
  }
}

__global__ __launch_bounds__(256) void k_build(const unsigned* __restrict__ binA,
                                               const unsigned* __restrict__ binB,
                                               const int* __restrict__ bOff,
                                               int* __restrict__ rpA, int* __restrict__ rpB,
                                               int* __restrict__ colA, int* __restrict__ colB,
                                               float* __restrict__ dinvA, float* __restrict__ dinvB) {
  int z = blockIdx.y, b = blockIdx.x, t = threadIdx.x;
  const unsigned* bin = z ? binB : binA;
  int* rp = z ? rpB : rpA;
  int* col = z ? colB : colA;
  float* dinv = z ? dinvB : dinvA;

  int e0 = bOff[z * (NB + 1) + b], e1 = bOff[z * (NB + 1) + b + 1];

  __shared__ int cnt[128];
  __shared__ int scn[128];
  __shared__ int cur[128];
  if (t < 128) cnt[t] = 0;
  __syncthreads();
  for (int e = e0 + t; e < e1; e += 256) atomicAdd(&cnt[bin[e] & 127], 1);
  __syncthreads();
  if (t < 128) scn[t] = cnt[t];
  __syncthreads();
  for (int o = 1; o < 128; o <<= 1) {
    int v = (t < 128 && t >= o) ? scn[t - o] : 0;
    __syncthreads();
    if (t < 128) scn[t] += v;
    __syncthreads();
  }
  if (t < 128) {
    int ex = scn[t] - cnt[t];
    cur[t] = ex;
    int node = b * 128 + t;
    if (node <= NN) rp[node] = e0 + ex;              // node==NN -> EE
    if (node < NN) dinv[node] = rsqrtf((float)(cnt[t] + 1));
  }
  __syncthreads();
  for (int e = e0 + t; e < e1; e += 256) {
    unsigned p = bin[e];
    int pos = e0 + atomicAdd(&cur[p & 127], 1);
    col[pos] = (int)(p >> 7);
  }
}

// ---------------- fused 3-power GEMM:  Z = Hin @ [w0|w1|w2]  (M=50000,K,N=192) ----------------

template<int K, bool F32IN>
__global__ __launch_bounds__(256) void k_gemm(const void* __restrict__ in0, const void* __restrict__ in1,
                                              const float* __restrict__ W0, const float* __restrict__ W1,
                                              unsigned short* __restrict__ Z0, unsigned short* __restrict__ Z1) {
  constexpr int KS = K / 32;
  constexpr int KP = K + 8;
  __shared__ unsigned short A_lds[64 * KP];

  int z = blockIdx.y;
  const void* Ain = z ? in1 : in0;
  const float* W = z ? W1 : W0;
  unsigned short* Zo = z ? Z1 : Z0;

  int t = threadIdx.x;
  int lane = t & 63, wv = t >> 6;
  int nloc = lane & 15, quad = lane >> 4;

  bf16x8 b[3][KS];
#pragma unroll
  for (int nt = 0; nt < 3; ++nt) {
    int ncol = wv * 48 + nt * 16 + nloc;                 // 0..191
    const float* wp = W + (ncol >> 6) * (K * 64) + (ncol & 63);
#pragma unroll
    for (int ks = 0; ks < KS; ++ks) {
      int kb = ks * 32 + quad * 8;
      us8 u;
#pragma unroll
      for (int i = 0; i < 8; ++i) u[i] = f2bf(wp[(kb + i) * 64]);
      b[nt][ks] = __builtin_bit_cast(bf16x8, u);
    }
  }

  for (int bm = blockIdx.x; bm < NTILES; bm += gridDim.x) {
    int m0 = bm * 64;
    __syncthreads();
#pragma unroll
    for (int it = 0; it < KS; ++it) {
      int c = it * 256 + t;
      int row = c / (K / 8);
      int kc  = c % (K / 8);
      int gr = m0 + row;
      us8 val;
      if (F32IN) {
        float4 v0 = make_float4(0, 0, 0, 0), v1 = make_float4(0, 0, 0, 0);
        if (gr < NN) {
          const float* Af = (const float*)Ain + (size_t)gr * K + kc * 8;
          v0 = *(const float4*)(Af);
          v1 = *(const float4*)(Af + 4);
        }
        val[0] = f2bf(v0.x); val[1] = f2bf(v0.y); val[2] = f2bf(v0.z); val[3] = f2bf(v0.w);
        val[4] = f2bf(v1.x); val[5] = f2bf(v1.y); val[6] = f2bf(v1.z); val[7] = f2bf(v1.w);
      } else {
        if (gr < NN) val = *(const us8*)((const unsigned short*)Ain + (size_t)gr * K + kc * 8);
        else         val = (us8)0;
      }
      *(us8*)(&A_lds[row * KP + kc * 8]) = val;
    }
    __syncthreads();

    f32x4 acc[4][3];
#pragma unroll
    for (int mt = 0; mt < 4; ++mt)
#pragma unroll
      for (int nt = 0; nt < 3; ++nt) acc[mt][nt] = (f32x4){0.f, 0.f, 0.f, 0.f};

#pragma unroll
    for (int ks = 0; ks < KS; ++ks) {
      bf16x8 a[4];
#pragma unroll
      for (int mt = 0; mt < 4; ++mt)
        a[mt] = *(const bf16x8*)(&A_lds[(mt * 16 + nloc) * KP + ks * 32 + quad * 8]);
#pragma unroll
      for (int mt = 0; mt < 4; ++mt)
#pragma unroll
        for (int nt = 0; nt < 3; ++nt)
          acc[mt][nt] = __builtin_amdgcn_mfma_f32_16x16x32_bf16(a[mt], b[nt][ks], acc[mt][nt], 0, 0, 0);
    }

#pragma unroll
    for (int mt = 0; mt < 4; ++mt) {
      int rowb = m0 + mt * 16 + quad * 4;
#pragma unroll
      for (int nt = 0; nt < 3; ++nt) {
        int colg = wv * 48 + nt * 16 + nloc;
#pragma unroll
        for (int r = 0; r < 4; ++r) {
          int rr = rowb + r;
          if (rr < NN) Zo[(size_t)rr * 192 + colg] = f2bf(acc[mt][nt][r]);
        }
      }
    }
  }
}

// ---------------- prop1: T = Ahat * Z[:,64:192]  (128 cols, bf16) ----------------

__global__ __launch_bounds__(256) void k_prop1(const unsigned short* __restrict__ Z0,
                                               const unsigned short* __restrict__ Z1,
                                               unsigned short* __restrict__ T0,
                                               unsigned short* __restrict__ T1,
                                               const int* __restrict__ rpA, const int* __restrict__ rpB,
                                               const int* __restrict__ colA, const int* __restrict__ colB,
                                               const float* __restrict__ dinvA, const float* __restrict__ dinvB) {
  int z = blockIdx.y;
  const unsigned short* Z = z ? Z1 : Z0;
  unsigned short* T = z ? T1 : T0;
  const int* rp = z ? rpB : rpA;
  const int* col = z ? colB : colA;
  const float* dinv = z ? dinvB : dinvA;

  int wv = threadIdx.x >> 6, lane = threadIdx.x & 63;
  int v = blockIdx.x * 4 + wv;
  if (v >= NN) return;
  v = __builtin_amdgcn_readfirstlane(v);

  int e0 = rp[v], e1 = rp[v + 1];
  float dv = dinv[v];

  unsigned selfv = ((const unsigned*)(Z + (size_t)v * 192 + 64))[lane];
  float ax = bflo(selfv) * dv, ay = bfhi(selfv) * dv;

  int e = e0;
  for (; e + 2 <= e1; e += 2) {
    int s0 = col[e], s1 = col[e + 1];
    float d0 = dinv[s0], d1 = dinv[s1];
    unsigned p0 = ((const unsigned*)(Z + (size_t)s0 * 192 + 64))[lane];
    unsigned p1 = ((const unsigned*)(Z + (size_t)s1 * 192 + 64))[lane];
    ax += d0 * bflo(p0) + d1 * bflo(p1);
    ay += d0 * bfhi(p0) + d1 * bfhi(p1);
  }
  if (e < e1) {
    int s0 = col[e];
    float d0 = dinv[s0];
    unsigned p0 = ((const unsigned*)(Z + (size_t)s0 * 192 + 64))[lane];
    ax += d0 * bflo(p0);
    ay += d0 * bfhi(p0);
  }
  ax *= dv; ay *= dv;
  unsigned o = (unsigned)f2bf(ax) | ((unsigned)f2bf(ay) << 16);
  ((unsigned*)(T + (size_t)v * 128))[lane] = o;
}

// ---------------- combine: U = Ahat * T[:,64:128]; out = tanh([Z0+b0 | T0+b1 | U+b2]) ----------------

template<bool FINAL>
__global__ __launch_bounds__(256) void k_combine(const unsigned short* __restrict__ Z0,
                                                 const unsigned short* __restrict__ Z1,
                                                 const unsigned short* __restrict__ T0,
                                                 const unsigned short* __restrict__ T1,
                                                 unsigned short* __restrict__ H0,
                                                 unsigned short* __restrict__ H1,
                                                 float* __restrict__ out,
                                                 const float* __restrict__ bia0, const float* __restrict__ bia1,
                                                 const int* __restrict__ rpA, const int* __restrict__ rpB,
                                                 const int* __restrict__ colA, const int* __restrict__ colB,
                                                 const float* __restrict__ dinvA, const float* __restrict__ dinvB) {
  int z = blockIdx.y;
  const unsigned short* Z = z ? Z1 : Z0;
  const unsigned short* T = z ? T1 : T0;
  unsigned short* H = z ? H1 : H0;
  const float* bias = z ? bia1 : bia0;
  const int* rp = z ? rpB : rpA;
  const int* col = z ? colB : colA;
  const float* dinv = z ? dinvB : dinvA;

  int wv = threadIdx.x >> 6, lane = threadIdx.x & 63;
  int v = blockIdx.x * 4 + wv;
  if (v >= NN) return;
  v = __builtin_amdgcn_readfirstlane(v);

  int e0 = rp[v], e1 = rp[v + 1];
  float dv = dinv[v];

  const unsigned short* Trow = T + (size_t)v * 128;
  float u = dv * bf2f(Trow[64 + lane]);   // self loop

  int e = e0;
  for (; e + 2 <= e1; e += 2) {
    int s0 = col[e], s1 = col[e + 1];
    float d0 = dinv[s0], d1 = dinv[s1];
    float t0 = bf2f(T[(size_t)s0 * 128 + 64 + lane]);
    float t1 = bf2f(T[(size_t)s1 * 128 + 64 + lane]);
    u += d0 * t0 + d1 * t1;
  }
  if (e < e1) {
    int s0 = col[e];
    u += dinv[s0] * bf2f(T[(size_t)s0 * 128 + 64 + lane]);
  }
  u *= dv;

  float p0 = fast_tanh(bf2f(Z[(size_t)v * 192 + lane]) + bias[lane]);
  float p1 = fast_tanh(bf2f(Trow[lane]) + bias[64 + lane]);
  float p2 = fast_tanh(u + bias[128 + lane]);

  if (FINAL) {
    float* o = out + (size_t)z * NN * 192 + (size_t)v * 192;
    o[lane] = p0; o[lane + 64] = p1; o[lane + 128] = p2;
  } else {
    unsigned short* h = H + (size_t)v * 192;
    h[lane] = f2bf(p0); h[lane + 64] = f2bf(p1); h[lane + 128] = f2bf(p2);
  }
}

// ---------------- host ----------------

extern "C" void kernel_launch(void* const* d_in, const int* in_sizes, int n_in,
                              void* d_out, int out_size, void* d_ws, size_t ws_size,
                              hipStream_t stream) {
  const float* x  = (const float*)d_in[0];
  const int* ei   = (const int*)d_in[1];
  const float* wout1 = (const float*)d_in[2];
  const float* bout1 = (const float*)d_in[3];
  const float* wout2 = (const float*)d_in[4];
  const float* bout2 = (const float*)d_in[5];
  const float* wout3 = (const float*)d_in[6];
  const float* bout3 = (const float*)d_in[7];
  const float* win1  = (const float*)d_in[8];
  const float* bin1  = (const float*)d_in[9];
  const float* win2  = (const float*)d_in[10];
  const float* bin2  = (const float*)d_in[11];
  const float* win3  = (const float*)d_in[12];
  const float* bin3  = (const float*)d_in[13];
  float* out = (float*)d_out;

  char* p = (char*)d_ws;
  auto alloc = [&](size_t bytes) { char* r = p; p += (bytes + 255) & ~(size_t)255; return r; };
  int* rpA   = (int*)alloc((size_t)(NN + 1) * 4);
  int* rpB   = (int*)alloc((size_t)(NN + 1) * 4);
  int* colA  = (int*)alloc((size_t)EE * 4);
  int* colB  = (int*)alloc((size_t)EE * 4);
  float* dinvA = (float*)alloc((size_t)NN * 4);
  float* dinvB = (float*)alloc((size_t)NN * 4);
  int* bCnt  = (int*)alloc((size_t)2 * NB * 4);
  int* bOff  = (int*)alloc((size_t)2 * (NB + 1) * 4);
  int* bCur  = (int*)alloc((size_t)2 * NB * 4);
  unsigned short* Z0 = (unsigned short*)alloc((size_t)NN * 192 * 2);
  unsigned short* Z1 = (unsigned short*)alloc((size_t)NN * 192 * 2);
  unsigned short* T0 = (unsigned short*)alloc((size_t)NN * 128 * 2);
  unsigned short* T1 = (unsigned short*)alloc((size_t)NN * 128 * 2);
  unsigned short* H0 = (unsigned short*)alloc((size_t)NN * 192 * 2);
  unsigned short* H1 = (unsigned short*)alloc((size_t)NN * 192 * 2);

  // bin arrays alias Z0/Z1 (Z written only after k_build completes)
  unsigned* binA = (unsigned*)Z0;
  unsigned* binB = (unsigned*)Z1;

  // ---- graph build (bucketed counting sort) ----
  hipMemsetAsync(bCnt, 0, (size_t)2 * NB * 4, stream);
  k_hist<<<391, 256, 0, stream>>>(ei, bCnt);
  k_bscan<<<2, 512, 0, stream>>>(bCnt, bOff, bCur);
  k_scatter<<<391, 256, 0, stream>>>(ei, bCur, binA, binB);
  k_build<<<dim3(NB, 2), 256, 0, stream>>>(binA, binB, bOff, rpA, rpB, colA, colB, dinvA, dinvB);

  dim3 gGemm(196, 2);
  dim3 gProp(12500, 2);

  // ---- layer 1 (K=256, fp32 input x shared by both encoders) ----
  k_gemm<256, true><<<gGemm, 256, 0, stream>>>(x, x, wout1, win1, Z0, Z1);
  k_prop1<<<gProp, 256, 0, stream>>>(Z0, Z1, T0, T1, rpA, rpB, colA, colB, dinvA, dinvB);
  k_combine<false><<<gProp, 256, 0, stream>>>(Z0, Z1, T0, T1, H0, H1, nullptr, bout1, bin1,
                                              rpA, rpB, colA, colB, dinvA, dinvB);
  // ---- layer 2 (K=192) ----
  k_gemm<192, false><<<gGemm, 256, 0, stream>>>(H0, H1, wout2, win2, Z0, Z1);
  k_prop1<<<gProp, 256, 0, stream>>>(Z0, Z1, T0, T1, rpA, rpB, colA, colB, dinvA, dinvB);
  k_combine<false><<<gProp, 256, 0, stream>>>(Z0, Z1, T0, T1, H0, H1, nullptr, bout2, bin2,
                                              rpA, rpB, colA, colB, dinvA, dinvB);
  // ---- layer 3 (K=192, writes fp32 d_out) ----
  k_gemm<192, false><<<gGemm, 256, 0, stream>>>(H0, H1, wout3, win3, Z0, Z1);
  k_prop1<<<gProp, 256, 0, stream>>>(Z0, Z1, T0, T1, rpA, rpB, colA, colB, dinvA, dinvB);
  k_combine<true><<<gProp, 256, 0, stream>>>(Z0, Z1, T0, T1, H0, H1, out, bout3, bin3,
                                             rpA, rpB, colA, colB, dinvA, dinvB);
}

// Round 3
// 565.406 us; speedup vs baseline: 1.4680x; 1.2172x over previous
//
#include <hip/hip_runtime.h>
#include <hip/hip_bf16.h>

#define NN 50000
#define EE 800000
#define NTILES 782   // ceil(50000/64)
#define NB 391       // ceil(50000/128) buckets of 128 nodes

typedef __bf16 bf16x8 __attribute__((ext_vector_type(8)));
typedef unsigned short us8 __attribute__((ext_vector_type(8)));
typedef float f32x4 __attribute__((ext_vector_type(4)));

__device__ __forceinline__ unsigned short f2bf(float f) {
  unsigned u = __float_as_uint(f);
  u += 0x7FFFu + ((u >> 16) & 1u);           // round-to-nearest-even
  return (unsigned short)(u >> 16);
}
__device__ __forceinline__ float bflo(unsigned u) { return __uint_as_float(u << 16); }
__device__ __forceinline__ float bfhi(unsigned u) { return __uint_as_float(u & 0xFFFF0000u); }
__device__ __forceinline__ float bf2f(unsigned short h) { return __uint_as_float(((unsigned)h) << 16); }
__device__ __forceinline__ float fast_tanh(float x) {
  float e = __expf(2.0f * x);
  return 1.0f - 2.0f / (e + 1.0f);
}

// ---------------- bucketed CSR build ----------------

__global__ __launch_bounds__(256) void k_hist(const int* __restrict__ ei, int* __restrict__ bCnt) {
  __shared__ int h[2 * NB];
  for (int i = threadIdx.x; i < 2 * NB; i += 256) h[i] = 0;
  __syncthreads();
  int base = blockIdx.x * 2048;
#pragma unroll
  for (int j = 0; j < 8; ++j) {
    int e = base + j * 256 + threadIdx.x;
    if (e < EE) {
      int s = ei[e], d = ei[EE + e];
      atomicAdd(&h[d >> 7], 1);
      atomicAdd(&h[NB + (s >> 7)], 1);
    }
  }
  __syncthreads();
  for (int i = threadIdx.x; i < 2 * NB; i += 256) {
    int c = h[i];
    if (c) atomicAdd(&bCnt[i], c);
  }
}

__global__ __launch_bounds__(512) void k_bscan(const int* __restrict__ bCnt,
                                               int* __restrict__ bOff, int* __restrict__ bCur) {
  __shared__ int sd[512];
  int z = blockIdx.x, t = threadIdx.x;
  sd[t] = (t < NB) ? bCnt[z * NB + t] : 0;
  __syncthreads();
  for (int o = 1; o < 512; o <<= 1) {
    int v = (t >= o) ? sd[t - o] : 0;
    __syncthreads();
    sd[t] += v;
    __syncthreads();
  }
  int ex = (t > 0) ? sd[t - 1] : 0;
  if (t < NB) { bOff[z * (NB + 1) + t] = ex; bCur[z * NB + t] = ex; }
  if (t == NB) bOff[z * (NB + 1) + NB] = ex;   // = total = EE
}

__global__ __launch_bounds__(256) void k_scatter(const int* __restrict__ ei,
                                                 int* __restrict__ bCur,
                                                 unsigned* __restrict__ binA,
                                                 unsigned* __restrict__ binB) {
  __shared__ int h[2 * NB];
  for (int i = threadIdx.x; i < 2 * NB; i += 256) h[i] = 0;
  __syncthreads();
  int base = blockIdx.x * 2048;
  int s[8], d[8], la[8], lb[8];
#pragma unroll
  for (int j = 0; j < 8; ++j) {
    int e = base + j * 256 + threadIdx.x;
    d[j] = -1;
    if (e < EE) {
      s[j] = ei[e]; d[j] = ei[EE + e];
      la[j] = atomicAdd(&h[d[j] >> 7], 1);
      lb[j] = atomicAdd(&h[NB + (s[j] >> 7)], 1);
    }
  }
  __syncthreads();
  for (int i = threadIdx.x; i < 2 * NB; i += 256) {
    int c = h[i];
    if (c) h[i] = atomicAdd(&bCur[i], c);
  }
  __syncthreads();
#pragma unroll
  for (int j = 0; j < 8; ++j) {
    if (d[j] >= 0) {
      int pa = h[d[j] >> 7] + la[j];
      binA[pa] = ((unsigned)s[j] << 7) | (unsigned)(d[j] & 127);
      int pb = h[NB + (s[j] >> 7)] + lb[j];
      binB[pb] = ((unsigned)d[j] << 7) | (unsigned)(s[j] & 127);
    }
  }
}

__global__ __launch_bounds__(256) void k_build(const unsigned* __restrict__ binA,
                                               const unsigned* __restrict__ binB,
                                               const int* __restrict__ bOff,
                                               int* __restrict__ rpA, int* __restrict__ rpB,
                                               int* __restrict__ colA, int* __restrict__ colB,
                                               float* __restrict__ dinvA, float* __restrict__ dinvB) {
  int z = blockIdx.y, b = blockIdx.x, t = threadIdx.x;
  const unsigned* bin = z ? binB : binA;
  int* rp = z ? rpB : rpA;
  int* col = z ? colB : colA;
  float* dinv = z ? dinvB : dinvA;

  int e0 = bOff[z * (NB + 1) + b], e1 = bOff[z * (NB + 1) + b + 1];

  __shared__ int cnt[128];
  __shared__ int scn[128];
  __shared__ int cur[128];
  if (t < 128) cnt[t] = 0;
  __syncthreads();
  for (int e = e0 + t; e < e1; e += 256) atomicAdd(&cnt[bin[e] & 127], 1);
  __syncthreads();
  if (t < 128) scn[t] = cnt[t];
  __syncthreads();
  for (int o = 1; o < 128; o <<= 1) {
    int v = (t < 128 && t >= o) ? scn[t - o] : 0;
    __syncthreads();
    if (t < 128) scn[t] += v;
    __syncthreads();
  }
  if (t < 128) {
    int ex = scn[t] - cnt[t];
    cur[t] = ex;
    int node = b * 128 + t;
    if (node <= NN) rp[node] = e0 + ex;
    if (node < NN) dinv[node] = rsqrtf((float)(cnt[t] + 1));
  }
  if (b == 0 && t < 8) col[EE + t] = 0;   // pad for 8-wide tail loads
  __syncthreads();
  for (int e = e0 + t; e < e1; e += 256) {
    unsigned p = bin[e];
    int pos = e0 + atomicAdd(&cur[p & 127], 1);
    col[pos] = (int)(p >> 7);
  }
}

// ---------------- fused 3-power GEMM:  Z = Hin @ [w0|w1|w2]  (M=50000,K,N=192) ----------------
// cols 64..191 of Z are written PRE-SCALED by dinv[row] (they are only ever
// gathered through A-hat); cols 0..63 unscaled (read directly as power-0 term).

template<int K, bool F32IN>
__global__ __launch_bounds__(256) void k_gemm(const void* __restrict__ in0, const void* __restrict__ in1,
                                              const float* __restrict__ W0, const float* __restrict__ W1,
                                              const float* __restrict__ dinvA, const float* __restrict__ dinvB,
                                              unsigned short* __restrict__ Z0, unsigned short* __restrict__ Z1) {
  constexpr int KS = K / 32;
  constexpr int KP = K + 8;
  __shared__ unsigned short A_lds[64 * KP];
  __shared__ float dvt[64];

  int z = blockIdx.y;
  const void* Ain = z ? in1 : in0;
  const float* W = z ? W1 : W0;
  const float* dinv = z ? dinvB : dinvA;
  unsigned short* Zo = z ? Z1 : Z0;

  int t = threadIdx.x;
  int lane = t & 63, wv = t >> 6;
  int nloc = lane & 15, quad = lane >> 4;

  bf16x8 b[3][KS];
#pragma unroll
  for (int nt = 0; nt < 3; ++nt) {
    int ncol = wv * 48 + nt * 16 + nloc;                 // 0..191
    const float* wp = W + (ncol >> 6) * (K * 64) + (ncol & 63);
#pragma unroll
    for (int ks = 0; ks < KS; ++ks) {
      int kb = ks * 32 + quad * 8;
      us8 u;
#pragma unroll
      for (int i = 0; i < 8; ++i) u[i] = f2bf(wp[(kb + i) * 64]);
      b[nt][ks] = __builtin_bit_cast(bf16x8, u);
    }
  }

  for (int bm = blockIdx.x; bm < NTILES; bm += gridDim.x) {
    int m0 = bm * 64;
    __syncthreads();
    if (t < 64) dvt[t] = (m0 + t < NN) ? dinv[m0 + t] : 0.f;
#pragma unroll
    for (int it = 0; it < KS; ++it) {
      int c = it * 256 + t;
      int row = c / (K / 8);
      int kc  = c % (K / 8);
      int gr = m0 + row;
      us8 val;
      if (F32IN) {
        float4 v0 = make_float4(0, 0, 0, 0), v1 = make_float4(0, 0, 0, 0);
        if (gr < NN) {
          const float* Af = (const float*)Ain + (size_t)gr * K + kc * 8;
          v0 = *(const float4*)(Af);
          v1 = *(const float4*)(Af + 4);
        }
        val[0] = f2bf(v0.x); val[1] = f2bf(v0.y); val[2] = f2bf(v0.z); val[3] = f2bf(v0.w);
        val[4] = f2bf(v1.x); val[5] = f2bf(v1.y); val[6] = f2bf(v1.z); val[7] = f2bf(v1.w);
      } else {
        if (gr < NN) val = *(const us8*)((const unsigned short*)Ain + (size_t)gr * K + kc * 8);
        else         val = (us8)0;
      }
      *(us8*)(&A_lds[row * KP + kc * 8]) = val;
    }
    __syncthreads();

    f32x4 acc[4][3];
#pragma unroll
    for (int mt = 0; mt < 4; ++mt)
#pragma unroll
      for (int nt = 0; nt < 3; ++nt) acc[mt][nt] = (f32x4){0.f, 0.f, 0.f, 0.f};

#pragma unroll
    for (int ks = 0; ks < KS; ++ks) {
      bf16x8 a[4];
#pragma unroll
      for (int mt = 0; mt < 4; ++mt)
        a[mt] = *(const bf16x8*)(&A_lds[(mt * 16 + nloc) * KP + ks * 32 + quad * 8]);
#pragma unroll
      for (int mt = 0; mt < 4; ++mt)
#pragma unroll
        for (int nt = 0; nt < 3; ++nt)
          acc[mt][nt] = __builtin_amdgcn_mfma_f32_16x16x32_bf16(a[mt], b[nt][ks], acc[mt][nt], 0, 0, 0);
    }

#pragma unroll
    for (int mt = 0; mt < 4; ++mt) {
      int rowb = m0 + mt * 16 + quad * 4;
#pragma unroll
      for (int nt = 0; nt < 3; ++nt) {
        int colg = wv * 48 + nt * 16 + nloc;
        bool sc = (wv * 48 + nt * 16) >= 64;     // whole 16-col block on one side
#pragma unroll
        for (int r = 0; r < 4; ++r) {
          int rr = rowb + r;
          float scale = sc ? dvt[mt * 16 + quad * 4 + r] : 1.0f;
          if (rr < NN) Zo[(size_t)rr * 192 + colg] = f2bf(acc[mt][nt][r] * scale);
        }
      }
    }
  }
}

// ---------------- prop1: T = Ahat * Z[:,64:192]  (gathers pre-scaled rows) ----------------
// T cols 0..63 stored as true T; cols 64..127 stored pre-scaled by dinv[v].

__global__ __launch_bounds__(256) void k_prop1(const unsigned short* __restrict__ Z0,
                                               const unsigned short* __restrict__ Z1,
                                               unsigned short* __restrict__ T0,
                                               unsigned short* __restrict__ T1,
                                               const int* __restrict__ rpA, const int* __restrict__ rpB,
                                               const int* __restrict__ colA, const int* __restrict__ colB,
                                               const float* __restrict__ dinvA, const float* __restrict__ dinvB) {
  int z = blockIdx.y;
  const unsigned short* Z = z ? Z1 : Z0;
  unsigned short* T = z ? T1 : T0;
  const int* rp = z ? rpB : rpA;
  const int* col = z ? colB : colA;
  const float* dinv = z ? dinvB : dinvA;

  int wv = threadIdx.x >> 6, lane = threadIdx.x & 63;
  int v = blockIdx.x * 4 + wv;
  v = __builtin_amdgcn_readfirstlane(v);

  int e0 = rp[v], e1 = rp[v + 1];
  float dv = dinv[v];

  unsigned selfv = ((const unsigned*)(Z + (size_t)v * 192 + 64))[lane];  // = dv*Z[v]
  float ax = bflo(selfv), ay = bfhi(selfv);

  int e = e0;
  if (e + 8 <= e1) {
    int idx[8];
#pragma unroll
    for (int j = 0; j < 8; ++j) idx[j] = col[e + j];
    e += 8;
    for (; e + 8 <= e1; e += 8) {
      int nidx[8];
#pragma unroll
      for (int j = 0; j < 8; ++j) nidx[j] = col[e + j];
      unsigned pp[8];
#pragma unroll
      for (int j = 0; j < 8; ++j) pp[j] = ((const unsigned*)(Z + (size_t)idx[j] * 192 + 64))[lane];
#pragma unroll
      for (int j = 0; j < 8; ++j) { ax += bflo(pp[j]); ay += bfhi(pp[j]); }
#pragma unroll
      for (int j = 0; j < 8; ++j) idx[j] = nidx[j];
    }
    unsigned pp[8];
#pragma unroll
    for (int j = 0; j < 8; ++j) pp[j] = ((const unsigned*)(Z + (size_t)idx[j] * 192 + 64))[lane];
#pragma unroll
    for (int j = 0; j < 8; ++j) { ax += bflo(pp[j]); ay += bfhi(pp[j]); }
  }
  int r = e1 - e;
  if (r > 0) {
    int idx[8];
#pragma unroll
    for (int j = 0; j < 8; ++j) idx[j] = col[e + j];   // padded: safe past e1
    unsigned pp[8];
#pragma unroll
    for (int j = 0; j < 8; ++j) pp[j] = ((const unsigned*)(Z + (size_t)idx[j] * 192 + 64))[lane];
#pragma unroll
    for (int j = 0; j < 8; ++j) if (j < r) { ax += bflo(pp[j]); ay += bfhi(pp[j]); }
  }

  ax *= dv; ay *= dv;                       // true T values
  float sc = (lane >= 32) ? dv : 1.0f;      // cols >=64 pre-scaled for next gather
  unsigned o = (unsigned)f2bf(ax * sc) | ((unsigned)f2bf(ay * sc) << 16);
  ((unsigned*)(T + (size_t)v * 128))[lane] = o;
}

// ---------------- combine: U = Ahat * T[:,64:128]; out = tanh([Z0+b0 | T0+b1 | U+b2]) ----------------

template<bool FINAL>
__global__ __launch_bounds__(256) void k_combine(const unsigned short* __restrict__ Z0,
                                                 const unsigned short* __restrict__ Z1,
                                                 const unsigned short* __restrict__ T0,
                                                 const unsigned short* __restrict__ T1,
                                                 unsigned short* __restrict__ H0,
                                                 unsigned short* __restrict__ H1,
                                                 float* __restrict__ out,
                                                 const float* __restrict__ bia0, const float* __restrict__ bia1,
                                                 const int* __restrict__ rpA, const int* __restrict__ rpB,
                                                 const int* __restrict__ colA, const int* __restrict__ colB,
                                                 const float* __restrict__ dinvA, const float* __restrict__ dinvB) {
  int z = blockIdx.y;
  const unsigned short* Z = z ? Z1 : Z0;
  const unsigned short* T = z ? T1 : T0;
  unsigned short* H = z ? H1 : H0;
  const float* bias = z ? bia1 : bia0;
  const int* rp = z ? rpB : rpA;
  const int* col = z ? colB : colA;
  const float* dinv = z ? dinvB : dinvA;

  int wv = threadIdx.x >> 6, lane = threadIdx.x & 63;
  int v = blockIdx.x * 4 + wv;
  v = __builtin_amdgcn_readfirstlane(v);

  int e0 = rp[v], e1 = rp[v + 1];
  float dv = dinv[v];

  const unsigned short* Trow = T + (size_t)v * 128;
  float u = bf2f(Trow[64 + lane]);          // = dv*T[v], the self-loop term

  int e = e0;
  if (e + 8 <= e1) {
    int idx[8];
#pragma unroll
    for (int j = 0; j < 8; ++j) idx[j] = col[e + j];
    e += 8;
    for (; e + 8 <= e1; e += 8) {
      int nidx[8];
#pragma unroll
      for (int j = 0; j < 8; ++j) nidx[j] = col[e + j];
      float pp[8];
#pragma unroll
      for (int j = 0; j < 8; ++j) pp[j] = bf2f(T[(size_t)idx[j] * 128 + 64 + lane]);
#pragma unroll
      for (int j = 0; j < 8; ++j) u += pp[j];
#pragma unroll
      for (int j = 0; j < 8; ++j) idx[j] = nidx[j];
    }
    float pp[8];
#pragma unroll
    for (int j = 0; j < 8; ++j) pp[j] = bf2f(T[(size_t)idx[j] * 128 + 64 + lane]);
#pragma unroll
    for (int j = 0; j < 8; ++j) u += pp[j];
  }
  int r = e1 - e;
  if (r > 0) {
    int idx[8];
#pragma unroll
    for (int j = 0; j < 8; ++j) idx[j] = col[e + j];   // padded: safe past e1
    float pp[8];
#pragma unroll
    for (int j = 0; j < 8; ++j) pp[j] = bf2f(T[(size_t)idx[j] * 128 + 64 + lane]);
#pragma unroll
    for (int j = 0; j < 8; ++j) if (j < r) u += pp[j];
  }
  u *= dv;

  float p0 = fast_tanh(bf2f(Z[(size_t)v * 192 + lane]) + bias[lane]);
  float p1 = fast_tanh(bf2f(Trow[lane]) + bias[64 + lane]);
  float p2 = fast_tanh(u + bias[128 + lane]);

  if (FINAL) {
    float* o = out + (size_t)z * NN * 192 + (size_t)v * 192;
    o[lane] = p0; o[lane + 64] = p1; o[lane + 128] = p2;
  } else {
    unsigned short* h = H + (size_t)v * 192;
    h[lane] = f2bf(p0); h[lane + 64] = f2bf(p1); h[lane + 128] = f2bf(p2);
  }
}

// ---------------- host ----------------

extern "C" void kernel_launch(void* const* d_in, const int* in_sizes, int n_in,
                              void* d_out, int out_size, void* d_ws, size_t ws_size,
                              hipStream_t stream) {
  const float* x  = (const float*)d_in[0];
  const int* ei   = (const int*)d_in[1];
  const float* wout1 = (const float*)d_in[2];
  const float* bout1 = (const float*)d_in[3];
  const float* wout2 = (const float*)d_in[4];
  const float* bout2 = (const float*)d_in[5];
  const float* wout3 = (const float*)d_in[6];
  const float* bout3 = (const float*)d_in[7];
  const float* win1  = (const float*)d_in[8];
  const float* bin1  = (const float*)d_in[9];
  const float* win2  = (const float*)d_in[10];
  const float* bin2  = (const float*)d_in[11];
  const float* win3  = (const float*)d_in[12];
  const float* bin3  = (const float*)d_in[13];
  float* out = (float*)d_out;

  char* p = (char*)d_ws;
  auto alloc = [&](size_t bytes) { char* r = p; p += (bytes + 255) & ~(size_t)255; return r; };
  int* rpA   = (int*)alloc((size_t)(NN + 1) * 4);
  int* rpB   = (int*)alloc((size_t)(NN + 1) * 4);
  int* colA  = (int*)alloc((size_t)(EE + 8) * 4);
  int* colB  = (int*)alloc((size_t)(EE + 8) * 4);
  float* dinvA = (float*)alloc((size_t)NN * 4);
  float* dinvB = (float*)alloc((size_t)NN * 4);
  int* bCnt  = (int*)alloc((size_t)2 * NB * 4);
  int* bOff  = (int*)alloc((size_t)2 * (NB + 1) * 4);
  int* bCur  = (int*)alloc((size_t)2 * NB * 4);
  unsigned short* Z0 = (unsigned short*)alloc((size_t)NN * 192 * 2);
  unsigned short* Z1 = (unsigned short*)alloc((size_t)NN * 192 * 2);
  unsigned short* T0 = (unsigned short*)alloc((size_t)NN * 128 * 2);
  unsigned short* T1 = (unsigned short*)alloc((size_t)NN * 128 * 2);
  unsigned short* H0 = (unsigned short*)alloc((size_t)NN * 192 * 2);
  unsigned short* H1 = (unsigned short*)alloc((size_t)NN * 192 * 2);

  unsigned* binA = (unsigned*)Z0;   // alias: bins dead before Z written
  unsigned* binB = (unsigned*)Z1;

  // ---- graph build (bucketed counting sort) ----
  hipMemsetAsync(bCnt, 0, (size_t)2 * NB * 4, stream);
  k_hist<<<391, 256, 0, stream>>>(ei, bCnt);
  k_bscan<<<2, 512, 0, stream>>>(bCnt, bOff, bCur);
  k_scatter<<<391, 256, 0, stream>>>(ei, bCur, binA, binB);
  k_build<<<dim3(NB, 2), 256, 0, stream>>>(binA, binB, bOff, rpA, rpB, colA, colB, dinvA, dinvB);

  dim3 gGemm(196, 2);
  dim3 gProp(12500, 2);

  // ---- layer 1 (K=256, fp32 input x shared by both encoders) ----
  k_gemm<256, true><<<gGemm, 256, 0, stream>>>(x, x, wout1, win1, dinvA, dinvB, Z0, Z1);
  k_prop1<<<gProp, 256, 0, stream>>>(Z0, Z1, T0, T1, rpA, rpB, colA, colB, dinvA, dinvB);
  k_combine<false><<<gProp, 256, 0, stream>>>(Z0, Z1, T0, T1, H0, H1, nullptr, bout1, bin1,
                                              rpA, rpB, colA, colB, dinvA, dinvB);
  // ---- layer 2 (K=192) ----
  k_gemm<192, false><<<gGemm, 256, 0, stream>>>(H0, H1, wout2, win2, dinvA, dinvB, Z0, Z1);
  k_prop1<<<gProp, 256, 0, stream>>>(Z0, Z1, T0, T1, rpA, rpB, colA, colB, dinvA, dinvB);
  k_combine<false><<<gProp, 256, 0, stream>>>(Z0, Z1, T0, T1, H0, H1, nullptr, bout2, bin2,
                                              rpA, rpB, colA, colB, dinvA, dinvB);
  // ---- layer 3 (K=192, writes fp32 d_out) ----
  k_gemm<192, false><<<gGemm, 256, 0, stream>>>(H0, H1, wout3, win3, dinvA, dinvB, Z0, Z1);
  k_prop1<<<gProp, 256, 0, stream>>>(Z0, Z1, T0, T1, rpA, rpB, colA, colB, dinvA, dinvB);
  k_combine<true><<<gProp, 256, 0, stream>>>(Z0, Z1, T0, T1, H0, H1, out, bout3, bin3,
                                             rpA, rpB, colA, colB, dinvA, dinvB);
}